// Round 1
// baseline (5708.112 us; speedup 1.0000x reference)
//
#include <hip/hip_runtime.h>
#include <cstdint>

#define NN0 80000
#define NE 1280000

static inline int cdiv(int a, int b){ return (a+b-1)/b; }

// h[n,Fout] = x[n,Fin] @ W[Fin,Fout]
__global__ void k_matmul(const float* __restrict__ x, const float* __restrict__ W,
                         float* __restrict__ h, int n, int Fin, int Fout) {
  int t = blockIdx.x*blockDim.x + threadIdx.x;
  if (t >= n*Fout) return;
  int i = t / Fout, f = t - i*Fout;
  float s = 0.f;
  for (int k2 = 0; k2 < Fin; k2++) s += x[i*Fin+k2]*W[k2*Fout+f];
  h[t] = s;
}

__global__ void k_fill(float* __restrict__ p, float v, int n){
  int t = blockIdx.x*blockDim.x + threadIdx.x;
  if (t < n) p[t] = v;
}

__global__ void k_deg(const int* __restrict__ dst, const float* __restrict__ ew,
                      float* __restrict__ deg, int ne) {
  int e = blockIdx.x*blockDim.x + threadIdx.x;
  if (e >= ne) return;
  float w = ew ? ew[e] : 1.0f;
  if (w != 0.f) atomicAdd(&deg[dst[e]], w);
}

__global__ void k_rsqrt_ip(float* __restrict__ p, int n){
  int t = blockIdx.x*blockDim.x + threadIdx.x;
  if (t < n) p[t] = 1.0f/sqrtf(p[t]);
}

// out[i,f] = fill * dinv[i]^2 * h[i,f]   (also serves as zero-free init before agg)
__global__ void k_selfinit(const float* __restrict__ h, const float* __restrict__ dinv,
                           float* __restrict__ out, float fill, int n, int F) {
  int t = blockIdx.x*blockDim.x + threadIdx.x;
  if (t >= n*F) return;
  int i = t / F;
  float d = dinv[i];
  out[t] = fill*d*d*h[t];
}

// one wave (64 lanes) per edge; lane = feature
__global__ void k_agg64(const int* __restrict__ src, const int* __restrict__ dst,
                        const float* __restrict__ ew, const float* __restrict__ dinv,
                        const float* __restrict__ h, float* __restrict__ out, int ne) {
  int t = blockIdx.x*blockDim.x + threadIdx.x;
  int e = t >> 6, f = t & 63;
  if (e >= ne) return;
  float w = ew ? ew[e] : 1.0f;
  if (w == 0.f) return;
  int s = src[e], d = dst[e];
  float nm = dinv[s]*w*dinv[d];
  atomicAdd(&out[d*64+f], nm*h[s*64+f]);
}

__global__ void k_agg1(const int* __restrict__ src, const int* __restrict__ dst,
                       const float* __restrict__ dinv, const float* __restrict__ h,
                       float* __restrict__ out, int ne) {
  int e = blockIdx.x*blockDim.x + threadIdx.x;
  if (e >= ne) return;
  int s = src[e], d = dst[e];
  atomicAdd(&out[d], dinv[s]*dinv[d]*h[s]);
}

__global__ void k_zero(float* __restrict__ p, int n){
  int t = blockIdx.x*blockDim.x + threadIdx.x;
  if (t < n) p[t] = 0.f;
}

// per-channel sum & sumsq over rows -> stats[0:64]=sum, stats[64:128]=sumsq
__global__ void k_bnstats(const float* __restrict__ x, float* __restrict__ stats, int n) {
  __shared__ float ls[64], lq[64];
  int f = threadIdx.x & 63, rl = threadIdx.x >> 6;
  if (threadIdx.x < 64) { ls[threadIdx.x] = 0.f; lq[threadIdx.x] = 0.f; }
  __syncthreads();
  float s = 0.f, q = 0.f;
  for (int i = blockIdx.x*4 + rl; i < n; i += gridDim.x*4) {
    float v = x[i*64+f]; s += v; q += v*v;
  }
  atomicAdd(&ls[f], s); atomicAdd(&lq[f], q);
  __syncthreads();
  if (threadIdx.x < 64) {
    atomicAdd(&stats[threadIdx.x], ls[threadIdx.x]);
    atomicAdd(&stats[64+threadIdx.x], lq[threadIdx.x]);
  }
}

__global__ void k_bnrelu(float* __restrict__ x, const float* __restrict__ stats,
                         const float* __restrict__ gamma, const float* __restrict__ beta,
                         int n) {
  int t = blockIdx.x*blockDim.x + threadIdx.x;
  if (t >= n*64) return;
  int f = t & 63;
  float inv_n = 1.0f/(float)n;
  float mu = stats[f]*inv_n;
  float var = stats[64+f]*inv_n - mu*mu;
  float v = gamma[f]*(x[t]-mu)*(1.0f/sqrtf(var+1e-5f)) + beta[f];
  x[t] = fmaxf(v, 0.f);
}

__global__ void k_score(const float* __restrict__ x, const float* __restrict__ pw,
                        float* __restrict__ score, int n) {
  int i = blockIdx.x*blockDim.x + threadIdx.x;
  if (i >= n) return;
  float s = 0.f, q = 0.f;
  for (int k2 = 0; k2 < 64; k2++){ float w = pw[k2]; s += x[i*64+k2]*w; q += w*w; }
  score[i] = fmaxf(s/sqrtf(q), 0.f);
}

// exact jax.lax.top_k order: rank(i) = #{score_j > score_i} + #{score_j==score_i, j<i}
__global__ void k_rank(const float* __restrict__ score, int* __restrict__ rank, int n) {
  __shared__ float sc[256];
  int i = blockIdx.x*256 + threadIdx.x;
  float my = (i < n) ? score[i] : -2.f;
  int r = 0;
  for (int base = 0; base < n; base += 256) {
    int j = base + threadIdx.x;
    sc[threadIdx.x] = (j < n) ? score[j] : -1.f;
    __syncthreads();
    int lim = min(256, n - base);
    for (int u = 0; u < lim; u++) {
      float v = sc[u];
      if (v > my || (v == my && (base+u) < i)) r++;
    }
    __syncthreads();
  }
  if (i < n) rank[i] = r;
}

__global__ void k_select_map(const int* __restrict__ rank, int* __restrict__ perm,
                             int* __restrict__ mapping, int n, int k) {
  int i = blockIdx.x*blockDim.x + threadIdx.x;
  if (i >= n) return;
  int r = rank[i];
  if (r < k) { mapping[i] = r; perm[r] = i; }
  else mapping[i] = -1;
}

__global__ void k_gather_scale(const float* __restrict__ x, const float* __restrict__ score,
                               const int* __restrict__ perm, float* __restrict__ xk, int k) {
  int t = blockIdx.x*blockDim.x + threadIdx.x;
  if (t >= k*64) return;
  int r = t >> 6, f = t & 63;
  int i = perm[r];
  xk[t] = x[i*64+f]*score[i];
}

__global__ void k_remap(const int* __restrict__ src, const int* __restrict__ dst,
                        const float* __restrict__ ew, const int* __restrict__ mapping,
                        int* __restrict__ nsrc, int* __restrict__ ndst,
                        float* __restrict__ new_ew, int ne) {
  int e = blockIdx.x*blockDim.x + threadIdx.x;
  if (e >= ne) return;
  int s = mapping[src[e]], d = mapping[dst[e]];
  float w = ew ? ew[e] : 1.f;
  bool valid = (s >= 0) && (d >= 0);
  nsrc[e] = valid ? s : 0;
  ndst[e] = valid ? d : 0;
  new_ew[e] = valid ? w : 0.f;
}

__global__ void k_scatter_add(const float* __restrict__ xup, const int* __restrict__ perm,
                              float* __restrict__ res, int k) {
  int t = blockIdx.x*blockDim.x + threadIdx.x;
  if (t >= k*64) return;
  int r = t >> 6, f = t & 63;
  res[perm[r]*64+f] += xup[t];
}

__global__ void k_sigmoid(float* __restrict__ p, int n){
  int t = blockIdx.x*blockDim.x + threadIdx.x;
  if (t < n) p[t] = 1.f/(1.f+expf(-p[t]));
}

extern "C" void kernel_launch(void* const* d_in, const int* in_sizes, int n_in,
                              void* d_out, int out_size, void* d_ws, size_t ws_size,
                              hipStream_t stream) {
  const float* x_in = (const float*)d_in[0];
  const int* ei = (const int*)d_in[1];
  const int* src0 = ei;
  const int* dst0 = ei + NE;
  const float* W_d[4] = {(const float*)d_in[2],(const float*)d_in[5],(const float*)d_in[8],(const float*)d_in[11]};
  const float* g_d[4] = {(const float*)d_in[3],(const float*)d_in[6],(const float*)d_in[9],(const float*)d_in[12]};
  const float* b_d[4] = {(const float*)d_in[4],(const float*)d_in[7],(const float*)d_in[10],(const float*)d_in[13]};
  const float* pw[3]  = {(const float*)d_in[14],(const float*)d_in[15],(const float*)d_in[16]};
  const float* W_u[2] = {(const float*)d_in[17],(const float*)d_in[20]};
  const float* g_u[2] = {(const float*)d_in[18],(const float*)d_in[21]};
  const float* b_u[2] = {(const float*)d_in[19],(const float*)d_in[22]};
  const float* W_out  = (const float*)d_in[23];
  float* out = (float*)d_out;

  float* base = (float*)d_ws;
  size_t off = 0;
  auto alloc = [&](size_t nf){ float* p = base + off; off += nf; return p; };
  float* x0 = alloc(5120000);          // 80000x64
  float* x1 = alloc(2560000);          // 40000x64
  float* x2 = alloc(1280000);          // 20000x64
  float* x3 = alloc(640000);           // 10000x64
  float* A  = alloc(2560000);          // ping buffer (max 40000x64)
  float* h  = alloc(5120000);          // matmul scratch
  int*   e1s = (int*)alloc(NE); int* e1d = (int*)alloc(NE); float* e1w = alloc(NE);
  int*   e2s = (int*)alloc(NE); int* e2d = (int*)alloc(NE); float* e2w = alloc(NE);
  int*   e3s = (int*)alloc(NE); int* e3d = (int*)alloc(NE); float* e3w = alloc(NE);
  float* deg   = alloc(NN0);
  float* score = alloc(NN0);
  int*   rank  = (int*)alloc(NN0);
  int*   mapv  = (int*)alloc(NN0);
  int*   p0 = (int*)alloc(40000);
  int*   p1 = (int*)alloc(20000);
  int*   p2 = (int*)alloc(10000);
  float* stats = alloc(128);
  (void)ws_size; (void)in_sizes; (void)n_in; (void)out_size;

  const int B = 256;

  auto conv64 = [&](const float* xin, const float* W, int Fin,
                    const int* es, const int* ed, const float* ew,
                    float fill, int n, float* dstb) {
    k_matmul  <<<cdiv(n*64,B), B, 0, stream>>>(xin, W, h, n, Fin, 64);
    k_fill    <<<cdiv(n,B),    B, 0, stream>>>(deg, fill, n);
    k_deg     <<<cdiv(NE,B),   B, 0, stream>>>(ed, ew, deg, NE);
    k_rsqrt_ip<<<cdiv(n,B),    B, 0, stream>>>(deg, n);
    k_selfinit<<<cdiv(n*64,B), B, 0, stream>>>(h, deg, dstb, fill, n, 64);
    k_agg64   <<<cdiv(NE*64,B),B, 0, stream>>>(es, ed, ew, deg, h, dstb, NE);
  };

  auto bn_relu = [&](float* xb, const float* g, const float* bt, int n) {
    k_zero   <<<1, 128, 0, stream>>>(stats, 128);
    k_bnstats<<<256, 256, 0, stream>>>(xb, stats, n);
    k_bnrelu <<<cdiv(n*64,B), B, 0, stream>>>(xb, stats, g, bt, n);
  };

  auto pool = [&](const float* xb, const float* w, int n, int k,
                  const int* es, const int* ed, const float* ew,
                  int* pm, int* ns, int* nd, float* nw, float* xk) {
    k_score      <<<cdiv(n,B),   B, 0, stream>>>(xb, w, score, n);
    k_rank       <<<cdiv(n,256), 256, 0, stream>>>(score, rank, n);
    k_select_map <<<cdiv(n,B),   B, 0, stream>>>(rank, pm, mapv, n, k);
    k_gather_scale<<<cdiv(k*64,B),B, 0, stream>>>(xb, score, pm, xk, k);
    k_remap      <<<cdiv(NE,B),  B, 0, stream>>>(es, ed, ew, mapv, ns, nd, nw, NE);
  };

  // ---- down path ----
  conv64(x_in, W_d[0], 3, src0, dst0, nullptr, 2.f, NN0, x0);
  bn_relu(x0, g_d[0], b_d[0], NN0);

  pool(x0, pw[0], NN0, 40000, src0, dst0, nullptr, p0, e1s, e1d, e1w, A);
  conv64(A, W_d[1], 64, e1s, e1d, e1w, 2.f, 40000, x1);
  bn_relu(x1, g_d[1], b_d[1], 40000);

  pool(x1, pw[1], 40000, 20000, e1s, e1d, e1w, p1, e2s, e2d, e2w, A);
  conv64(A, W_d[2], 64, e2s, e2d, e2w, 2.f, 20000, x2);
  bn_relu(x2, g_d[2], b_d[2], 20000);

  pool(x2, pw[2], 20000, 10000, e2s, e2d, e2w, p2, e3s, e3d, e3w, A);
  conv64(A, W_d[3], 64, e3s, e3d, e3w, 2.f, 10000, x3);
  bn_relu(x3, g_d[3], b_d[3], 10000);

  // ---- up path ----
  k_scatter_add<<<cdiv(10000*64,B), B, 0, stream>>>(x3, p2, x2, 10000);
  conv64(x2, W_u[0], 64, e2s, e2d, e2w, 2.f, 20000, A);
  bn_relu(A, g_u[0], b_u[0], 20000);

  k_scatter_add<<<cdiv(20000*64,B), B, 0, stream>>>(A, p1, x1, 20000);
  conv64(x1, W_u[1], 64, e1s, e1d, e1w, 2.f, 40000, A);
  bn_relu(A, g_u[1], b_u[1], 40000);

  k_scatter_add<<<cdiv(40000*64,B), B, 0, stream>>>(A, p0, x0, 40000);

  // ---- final conv (fill = 1.0) + sigmoid ----
  float* h1 = score;  // reuse
  k_matmul  <<<cdiv(NN0,B), B, 0, stream>>>(x0, W_out, h1, NN0, 64, 1);
  k_fill    <<<cdiv(NN0,B), B, 0, stream>>>(deg, 1.f, NN0);
  k_deg     <<<cdiv(NE,B),  B, 0, stream>>>(dst0, (const float*)nullptr, deg, NE);
  k_rsqrt_ip<<<cdiv(NN0,B), B, 0, stream>>>(deg, NN0);
  k_selfinit<<<cdiv(NN0,B), B, 0, stream>>>(h1, deg, out, 1.f, NN0, 1);
  k_agg1    <<<cdiv(NE,B),  B, 0, stream>>>(src0, dst0, deg, h1, out, NE);
  k_sigmoid <<<cdiv(NN0,B), B, 0, stream>>>(out, NN0);
}

// Round 2
// 3962.151 us; speedup vs baseline: 1.4407x; 1.4407x over previous
//
#include <hip/hip_runtime.h>
#include <cstdint>
#include <utility>

#define NN0 80000
#define NE 1280000

static inline int cdiv(int a, int b){ return (a+b-1)/b; }

// h[n,Fout] = x[n,Fin] @ W[Fin,Fout]
__global__ void k_matmul(const float* __restrict__ x, const float* __restrict__ W,
                         float* __restrict__ h, int n, int Fin, int Fout) {
  int t = blockIdx.x*blockDim.x + threadIdx.x;
  if (t >= n*Fout) return;
  int i = t / Fout, f = t - i*Fout;
  float s = 0.f;
  for (int k2 = 0; k2 < Fin; k2++) s += x[i*Fin+k2]*W[k2*Fout+f];
  h[t] = s;
}

__global__ void k_zero_f(float* __restrict__ p, int n){
  int t = blockIdx.x*blockDim.x + threadIdx.x;
  if (t < n) p[t] = 0.f;
}
__global__ void k_zero_i(int* __restrict__ p, int n){
  int t = blockIdx.x*blockDim.x + threadIdx.x;
  if (t < n) p[t] = 0;
}

// degree sum (edge weight == 1 throughout the net), full edge list
__global__ void k_deg_full(const int* __restrict__ dst, float* __restrict__ deg, int ne) {
  int e = blockIdx.x*blockDim.x + threadIdx.x;
  if (e >= ne) return;
  atomicAdd(&deg[dst[e]], 1.0f);
}
// degree sum over compacted edges
__global__ void k_deg_c(const int* __restrict__ dst, const int* __restrict__ cnt,
                        float* __restrict__ deg) {
  int total = *cnt;
  for (int e = blockIdx.x*blockDim.x + threadIdx.x; e < total; e += gridDim.x*blockDim.x)
    atomicAdd(&deg[dst[e]], 1.0f);
}

__global__ void k_dinv(const float* __restrict__ degsum, float* __restrict__ dinv,
                       float fill, int n){
  int t = blockIdx.x*blockDim.x + threadIdx.x;
  if (t < n) dinv[t] = 1.0f/sqrtf(degsum[t] + fill);
}

// out[i,f] = fill * dinv[i]^2 * h[i,f]  (initializes out, no pre-zero needed)
__global__ void k_selfinit(const float* __restrict__ h, const float* __restrict__ dinv,
                           float* __restrict__ out, float fill, int n, int F) {
  int t = blockIdx.x*blockDim.x + threadIdx.x;
  if (t >= n*F) return;
  int i = t / F;
  float d = dinv[i];
  out[t] = fill*d*d*h[t];
}

__global__ void k_norm_full(const int* __restrict__ src, const int* __restrict__ dst,
                            const float* __restrict__ dinv, float* __restrict__ nm, int ne){
  int e = blockIdx.x*blockDim.x + threadIdx.x;
  if (e >= ne) return;
  nm[e] = dinv[src[e]]*dinv[dst[e]];
}
__global__ void k_norm_c(const int* __restrict__ src, const int* __restrict__ dst,
                         const float* __restrict__ dinv, float* __restrict__ nm,
                         const int* __restrict__ cnt){
  int total = *cnt;
  for (int e = blockIdx.x*blockDim.x + threadIdx.x; e < total; e += gridDim.x*blockDim.x)
    nm[e] = dinv[src[e]]*dinv[dst[e]];
}

// 16 threads per edge, float4 per thread
__global__ void k_agg_full(const int* __restrict__ src, const int* __restrict__ dst,
                           const float* __restrict__ nm, const float* __restrict__ h,
                           float* __restrict__ out) {
  int t = blockIdx.x*blockDim.x + threadIdx.x;
  int e = t >> 4, q = (t & 15)*4;
  if (e >= NE) return;
  float w = nm[e];
  int s = src[e], d = dst[e];
  const float4 hv = *(const float4*)(h + s*64 + q);
  float* o = out + d*64 + q;
  atomicAdd(o+0, w*hv.x); atomicAdd(o+1, w*hv.y);
  atomicAdd(o+2, w*hv.z); atomicAdd(o+3, w*hv.w);
}
__global__ void k_agg_c(const int* __restrict__ src, const int* __restrict__ dst,
                        const float* __restrict__ nm, const float* __restrict__ h,
                        float* __restrict__ out, const int* __restrict__ cnt) {
  int total = (*cnt)*16;
  for (int t = blockIdx.x*blockDim.x + threadIdx.x; t < total; t += gridDim.x*blockDim.x){
    int e = t >> 4, q = (t & 15)*4;
    float w = nm[e];
    int s = src[e], d = dst[e];
    const float4 hv = *(const float4*)(h + s*64 + q);
    float* o = out + d*64 + q;
    atomicAdd(o+0, w*hv.x); atomicAdd(o+1, w*hv.y);
    atomicAdd(o+2, w*hv.z); atomicAdd(o+3, w*hv.w);
  }
}

__global__ void k_agg1(const int* __restrict__ src, const int* __restrict__ dst,
                       const float* __restrict__ dinv, const float* __restrict__ h,
                       float* __restrict__ out, int ne) {
  int e = blockIdx.x*blockDim.x + threadIdx.x;
  if (e >= ne) return;
  int s = src[e], d = dst[e];
  atomicAdd(&out[d], dinv[s]*dinv[d]*h[s]);
}

// per-channel sum & sumsq over rows -> stats[0:64]=sum, stats[64:128]=sumsq
__global__ void k_bnstats(const float* __restrict__ x, float* __restrict__ stats, int n) {
  __shared__ float ls[64], lq[64];
  int f = threadIdx.x & 63, rl = threadIdx.x >> 6;
  if (threadIdx.x < 64) { ls[threadIdx.x] = 0.f; lq[threadIdx.x] = 0.f; }
  __syncthreads();
  float s = 0.f, q = 0.f;
  for (int i = blockIdx.x*4 + rl; i < n; i += gridDim.x*4) {
    float v = x[i*64+f]; s += v; q += v*v;
  }
  atomicAdd(&ls[f], s); atomicAdd(&lq[f], q);
  __syncthreads();
  if (threadIdx.x < 64) {
    atomicAdd(&stats[threadIdx.x], ls[threadIdx.x]);
    atomicAdd(&stats[64+threadIdx.x], lq[threadIdx.x]);
  }
}

__global__ void k_bnrelu(float* __restrict__ x, const float* __restrict__ stats,
                         const float* __restrict__ gamma, const float* __restrict__ beta,
                         int n) {
  int t = blockIdx.x*blockDim.x + threadIdx.x;
  if (t >= n*64) return;
  int f = t & 63;
  float inv_n = 1.0f/(float)n;
  float mu = stats[f]*inv_n;
  float var = stats[64+f]*inv_n - mu*mu;
  float v = gamma[f]*(x[t]-mu)*(1.0f/sqrtf(var+1e-5f)) + beta[f];
  x[t] = fmaxf(v, 0.f);
}

__global__ void k_score(const float* __restrict__ x, const float* __restrict__ pw,
                        float* __restrict__ score, int n) {
  int i = blockIdx.x*blockDim.x + threadIdx.x;
  if (i >= n) return;
  float s = 0.f, q = 0.f;
  for (int k2 = 0; k2 < 64; k2++){ float w = pw[k2]; s += x[i*64+k2]*w; q += w*w; }
  score[i] = fmaxf(s/sqrtf(q), 0.f);
}

// ---- stable LSD radix sort (descending score, ties index-asc) ----
// key = ~float_bits(score); scores >= 0 so bits are monotone; ascending stable
// sort of key == descending stable sort of score == jax.lax.top_k order.
__global__ void k_radix_init(const float* __restrict__ score, unsigned* __restrict__ key,
                             int* __restrict__ idx, int n, int P){
  int g = blockIdx.x*blockDim.x + threadIdx.x;
  if (g >= P) return;
  if (g < n) { key[g] = ~__float_as_uint(score[g]); idx[g] = g; }
  else       { key[g] = 0xFFFFFFFFu; idx[g] = 0; }   // padding sorts last (stable)
}

__global__ void k_radix_hist(const unsigned* __restrict__ key, unsigned* __restrict__ hist,
                             int shift, int nblk){
  __shared__ unsigned lh[256];
  lh[threadIdx.x] = 0; __syncthreads();
  int g = blockIdx.x*256 + threadIdx.x;
  unsigned d = (key[g] >> shift) & 255u;
  atomicAdd(&lh[d], 1u);
  __syncthreads();
  hist[threadIdx.x*nblk + blockIdx.x] = lh[threadIdx.x];
}

// exclusive scan over hist in (bin-major, block-minor) order; 1 block, 256 thr
__global__ void k_radix_scan(unsigned* __restrict__ hist, int nblk){
  __shared__ unsigned bs[256];
  int d = threadIdx.x;
  unsigned s = 0;
  for (int b = 0; b < nblk; b++) s += hist[d*nblk + b];
  bs[d] = s; __syncthreads();
  if (d == 0){ unsigned acc = 0; for (int i = 0; i < 256; i++){ unsigned t = bs[i]; bs[i] = acc; acc += t; } }
  __syncthreads();
  unsigned acc = bs[d];
  for (int b = 0; b < nblk; b++){ unsigned t = hist[d*nblk + b]; hist[d*nblk + b] = acc; acc += t; }
}

__global__ void k_radix_scatter(const unsigned* __restrict__ keyin, const int* __restrict__ idxin,
                                unsigned* __restrict__ keyout, int* __restrict__ idxout,
                                const unsigned* __restrict__ hist, int shift, int nblk){
  __shared__ unsigned ld[256];
  int g = blockIdx.x*256 + threadIdx.x;
  unsigned kk = keyin[g];
  int id = idxin[g];
  unsigned d = (kk >> shift) & 255u;
  ld[threadIdx.x] = d; __syncthreads();
  unsigned r = 0;
  for (int u = 0; u < threadIdx.x; u++) if (ld[u] == d) r++;   // stable local rank
  unsigned pos = hist[d*nblk + blockIdx.x] + r;
  keyout[pos] = kk; idxout[pos] = id;
}

__global__ void k_select_sorted(const int* __restrict__ idxs, int* __restrict__ perm,
                                int* __restrict__ mapping, int n, int k){
  int r = blockIdx.x*blockDim.x + threadIdx.x;
  if (r >= n) return;
  int i = idxs[r];
  mapping[i] = (r < k) ? r : -1;
  if (r < k) perm[r] = i;
}

__global__ void k_gather_scale(const float* __restrict__ x, const float* __restrict__ score,
                               const int* __restrict__ perm, float* __restrict__ xk, int k) {
  int t = blockIdx.x*blockDim.x + threadIdx.x;
  if (t >= k*64) return;
  int r = t >> 6, f = t & 63;
  int i = perm[r];
  xk[t] = x[i*64+f]*score[i];
}

// compact valid remapped edges (weights are identically 1.0 -> drop invalid)
__global__ void k_remap_c(const int* __restrict__ src, const int* __restrict__ dst,
                          const int* __restrict__ pcnt, int pfb,
                          const int* __restrict__ mapping,
                          int* __restrict__ ns, int* __restrict__ nd, int* __restrict__ cnt){
  int total = pcnt ? *pcnt : pfb;
  for (int e = blockIdx.x*blockDim.x + threadIdx.x; e < total; e += gridDim.x*blockDim.x){
    int s = mapping[src[e]], d = mapping[dst[e]];
    if (s >= 0 && d >= 0){
      int p = atomicAdd(cnt, 1);
      ns[p] = s; nd[p] = d;
    }
  }
}

__global__ void k_scatter_add(const float* __restrict__ xup, const int* __restrict__ perm,
                              float* __restrict__ res, int k) {
  int t = blockIdx.x*blockDim.x + threadIdx.x;
  if (t >= k*64) return;
  int r = t >> 6, f = t & 63;
  res[perm[r]*64+f] += xup[t];
}

__global__ void k_sigmoid(float* __restrict__ p, int n){
  int t = blockIdx.x*blockDim.x + threadIdx.x;
  if (t < n) p[t] = 1.f/(1.f+expf(-p[t]));
}

extern "C" void kernel_launch(void* const* d_in, const int* in_sizes, int n_in,
                              void* d_out, int out_size, void* d_ws, size_t ws_size,
                              hipStream_t stream) {
  const float* x_in = (const float*)d_in[0];
  const int* ei = (const int*)d_in[1];
  const int* src0 = ei;
  const int* dst0 = ei + NE;
  const float* W_d[4] = {(const float*)d_in[2],(const float*)d_in[5],(const float*)d_in[8],(const float*)d_in[11]};
  const float* g_d[4] = {(const float*)d_in[3],(const float*)d_in[6],(const float*)d_in[9],(const float*)d_in[12]};
  const float* b_d[4] = {(const float*)d_in[4],(const float*)d_in[7],(const float*)d_in[10],(const float*)d_in[13]};
  const float* pw[3]  = {(const float*)d_in[14],(const float*)d_in[15],(const float*)d_in[16]};
  const float* W_u[2] = {(const float*)d_in[17],(const float*)d_in[20]};
  const float* g_u[2] = {(const float*)d_in[18],(const float*)d_in[21]};
  const float* b_u[2] = {(const float*)d_in[19],(const float*)d_in[22]};
  const float* W_out  = (const float*)d_in[23];
  float* out = (float*)d_out;

  float* base = (float*)d_ws;
  size_t off = 0;
  auto alloc = [&](size_t nf){ float* p = base + off; off += nf; return p; };
  float* x0 = alloc(5120000);
  float* x1 = alloc(2560000);
  float* x2 = alloc(1280000);
  float* x3 = alloc(640000);
  float* A  = alloc(2560000);
  float* h  = alloc(5120000);
  int* e1s = (int*)alloc(NE); int* e1d = (int*)alloc(NE);
  int* e2s = (int*)alloc(NE); int* e2d = (int*)alloc(NE);
  int* e3s = (int*)alloc(NE); int* e3d = (int*)alloc(NE);
  float* nm    = alloc(NE);
  float* deg0s = alloc(NN0);
  float* deg1s = alloc(40000);
  float* deg2s = alloc(20000);
  float* deg3s = alloc(10000);
  float* dinv  = alloc(NN0);
  float* score = alloc(NN0);
  int* mapv = (int*)alloc(NN0);
  int* p0 = (int*)alloc(40000);
  int* p1 = (int*)alloc(20000);
  int* p2 = (int*)alloc(10000);
  float* stats = alloc(128);
  int* cnts = (int*)alloc(4);           // cnts[0..2] = edge counts L1..L3
  unsigned* keyA = (unsigned*)alloc(80128);
  unsigned* keyB = (unsigned*)alloc(80128);
  int* idxA = (int*)alloc(80128);
  int* idxB = (int*)alloc(80128);
  unsigned* hist = (unsigned*)alloc(80128);
  (void)ws_size; (void)in_sizes; (void)n_in; (void)out_size;

  const int B = 256;

  k_zero_i<<<1, 64, 0, stream>>>(cnts, 4);

  auto conv = [&](const float* xin, const float* W, int Fin, int n, float fill,
                  const float* degsum, const int* es, const int* ed,
                  const int* cnt, float* dstb){
    k_matmul  <<<cdiv(n*64,B), B, 0, stream>>>(xin, W, h, n, Fin, 64);
    k_dinv    <<<cdiv(n,B),    B, 0, stream>>>(degsum, dinv, fill, n);
    k_selfinit<<<cdiv(n*64,B), B, 0, stream>>>(h, dinv, dstb, fill, n, 64);
    if (cnt) {
      k_norm_c<<<256,  B, 0, stream>>>(es, ed, dinv, nm, cnt);
      k_agg_c <<<2048, B, 0, stream>>>(es, ed, nm, h, dstb, cnt);
    } else {
      k_norm_full<<<cdiv(NE,B),    B, 0, stream>>>(es, ed, dinv, nm, NE);
      k_agg_full <<<cdiv(NE*16,B), B, 0, stream>>>(es, ed, nm, h, dstb);
    }
  };

  auto bn_relu = [&](float* xb, const float* g, const float* bt, int n) {
    k_zero_f <<<1, 128, 0, stream>>>(stats, 128);
    k_bnstats<<<256, 256, 0, stream>>>(xb, stats, n);
    k_bnrelu <<<cdiv(n*64,B), B, 0, stream>>>(xb, stats, g, bt, n);
  };

  auto pool = [&](const float* xb, const float* w, int n, int k,
                  const int* es, const int* ed, const int* pcnt,
                  int* pm, int* ns, int* nd, int* cnt, float* xk) {
    k_score<<<cdiv(n,B), B, 0, stream>>>(xb, w, score, n);
    int nblk = cdiv(n, 256), P = nblk*256;
    k_radix_init<<<cdiv(P,B), B, 0, stream>>>(score, keyA, idxA, n, P);
    unsigned* ka = keyA; int* ia = idxA; unsigned* kb = keyB; int* ib = idxB;
    for (int pass = 0; pass < 4; pass++) {
      k_radix_hist   <<<nblk, 256, 0, stream>>>(ka, hist, pass*8, nblk);
      k_radix_scan   <<<1,    256, 0, stream>>>(hist, nblk);
      k_radix_scatter<<<nblk, 256, 0, stream>>>(ka, ia, kb, ib, hist, pass*8, nblk);
      std::swap(ka, kb); std::swap(ia, ib);
    }
    k_select_sorted<<<cdiv(n,B), B, 0, stream>>>(ia == idxA ? idxA : idxB, pm, mapv, n, k);
    k_gather_scale <<<cdiv(k*64,B), B, 0, stream>>>(xb, score, pm, xk, k);
    k_remap_c      <<<1024, B, 0, stream>>>(es, ed, pcnt, NE, mapv, ns, nd, cnt);
  };

  // degree sums (edge weight == 1): level 0 once, reused for first & final conv
  k_zero_f  <<<cdiv(NN0,B), B, 0, stream>>>(deg0s, NN0);
  k_deg_full<<<cdiv(NE,B),  B, 0, stream>>>(dst0, deg0s, NE);

  // ---- down path ----
  conv(x_in, W_d[0], 3, NN0, 2.f, deg0s, src0, dst0, nullptr, x0);
  bn_relu(x0, g_d[0], b_d[0], NN0);

  pool(x0, pw[0], NN0, 40000, src0, dst0, nullptr, p0, e1s, e1d, &cnts[0], A);
  k_zero_f<<<cdiv(40000,B), B, 0, stream>>>(deg1s, 40000);
  k_deg_c <<<256, B, 0, stream>>>(e1d, &cnts[0], deg1s);
  conv(A, W_d[1], 64, 40000, 2.f, deg1s, e1s, e1d, &cnts[0], x1);
  bn_relu(x1, g_d[1], b_d[1], 40000);

  pool(x1, pw[1], 40000, 20000, e1s, e1d, &cnts[0], p1, e2s, e2d, &cnts[1], A);
  k_zero_f<<<cdiv(20000,B), B, 0, stream>>>(deg2s, 20000);
  k_deg_c <<<256, B, 0, stream>>>(e2d, &cnts[1], deg2s);
  conv(A, W_d[2], 64, 20000, 2.f, deg2s, e2s, e2d, &cnts[1], x2);
  bn_relu(x2, g_d[2], b_d[2], 20000);

  pool(x2, pw[2], 20000, 10000, e2s, e2d, &cnts[1], p2, e3s, e3d, &cnts[2], A);
  k_zero_f<<<cdiv(10000,B), B, 0, stream>>>(deg3s, 10000);
  k_deg_c <<<256, B, 0, stream>>>(e3d, &cnts[2], deg3s);
  conv(A, W_d[3], 64, 10000, 2.f, deg3s, e3s, e3d, &cnts[2], x3);
  bn_relu(x3, g_d[3], b_d[3], 10000);

  // ---- up path ----
  k_scatter_add<<<cdiv(10000*64,B), B, 0, stream>>>(x3, p2, x2, 10000);
  conv(x2, W_u[0], 64, 20000, 2.f, deg2s, e2s, e2d, &cnts[1], A);
  bn_relu(A, g_u[0], b_u[0], 20000);

  k_scatter_add<<<cdiv(20000*64,B), B, 0, stream>>>(A, p1, x1, 20000);
  conv(x1, W_u[1], 64, 40000, 2.f, deg1s, e1s, e1d, &cnts[0], A);
  bn_relu(A, g_u[1], b_u[1], 40000);

  k_scatter_add<<<cdiv(40000*64,B), B, 0, stream>>>(A, p0, x0, 40000);

  // ---- final conv (fill = 1.0) + sigmoid ----
  float* h1 = score;  // reuse
  k_matmul  <<<cdiv(NN0,B), B, 0, stream>>>(x0, W_out, h1, NN0, 64, 1);
  k_dinv    <<<cdiv(NN0,B), B, 0, stream>>>(deg0s, dinv, 1.f, NN0);
  k_selfinit<<<cdiv(NN0,B), B, 0, stream>>>(h1, dinv, out, 1.f, NN0, 1);
  k_agg1    <<<cdiv(NE,B),  B, 0, stream>>>(src0, dst0, dinv, h1, out, NE);
  k_sigmoid <<<cdiv(NN0,B), B, 0, stream>>>(out, NN0);
}

// Round 3
// 2380.553 us; speedup vs baseline: 2.3978x; 1.6644x over previous
//
#include <hip/hip_runtime.h>
#include <cstdint>
#include <utility>

#define NN0 80000
#define NE 1280000

static inline int cdiv(int a, int b){ return (a+b-1)/b; }

// h[n,Fout] = x[n,Fin] @ W[Fin,Fout]
__global__ void k_matmul(const float* __restrict__ x, const float* __restrict__ W,
                         float* __restrict__ h, int n, int Fin, int Fout) {
  int t = blockIdx.x*blockDim.x + threadIdx.x;
  if (t >= n*Fout) return;
  int i = t / Fout, f = t - i*Fout;
  float s = 0.f;
  for (int k2 = 0; k2 < Fin; k2++) s += x[i*Fin+k2]*W[k2*Fout+f];
  h[t] = s;
}

__global__ void k_zero_f(float* __restrict__ p, int n){
  int t = blockIdx.x*blockDim.x + threadIdx.x;
  if (t < n) p[t] = 0.f;
}
__global__ void k_zero_i(int* __restrict__ p, int n){
  int t = blockIdx.x*blockDim.x + threadIdx.x;
  if (t < n) p[t] = 0;
}

// ---- CSR build, level 0 (full input edge list) ----
__global__ void k_hist_full(const int* __restrict__ dst, int* __restrict__ indeg, int ne){
  int e = blockIdx.x*blockDim.x + threadIdx.x;
  if (e < ne) atomicAdd(&indeg[dst[e]], 1);
}
__global__ void k_scatter_full(const int* __restrict__ src, const int* __restrict__ dst,
                               int* __restrict__ cursor, int* __restrict__ col, int ne){
  int e = blockIdx.x*blockDim.x + threadIdx.x;
  if (e >= ne) return;
  int pos = atomicAdd(&cursor[dst[e]], 1);
  col[pos] = src[e];
}

// exclusive scan of indeg[0..n) -> rp[0..n], also copies into cursor
__global__ void k_scan(const int* __restrict__ indeg, int* __restrict__ rp,
                       int* __restrict__ cursor, int n){
  __shared__ int bs[256];
  int chunk = (n + 255) / 256;
  int lo = threadIdx.x * chunk, hi = min(lo + chunk, n);
  int s = 0;
  for (int i = lo; i < hi; i++) s += indeg[i];
  bs[threadIdx.x] = s; __syncthreads();
  if (threadIdx.x == 0){ int acc = 0; for (int i = 0; i < 256; i++){ int t = bs[i]; bs[i] = acc; acc += t; } }
  __syncthreads();
  int acc = bs[threadIdx.x];
  for (int i = lo; i < hi; i++){ rp[i] = acc; cursor[i] = acc; acc += indeg[i]; }
  if (hi == n) rp[n] = acc;
}

// ---- CSR build for pooled level from parent CSR + injective mapping ----
// mapping is injective => each child row owned by exactly one parent node:
// no atomics, deterministic edge order.
__global__ void k_hist_mapped(const int* __restrict__ rp_p, const int* __restrict__ col_p,
                              const int* __restrict__ mapv, int* __restrict__ indeg, int np){
  int d = blockIdx.x*blockDim.x + threadIdx.x;
  if (d >= np) return;
  int md = mapv[d];
  if (md < 0) return;
  int c = 0, e = rp_p[d+1];
  for (int j = rp_p[d]; j < e; j++) if (mapv[col_p[j]] >= 0) c++;
  indeg[md] = c;
}
__global__ void k_scatter_mapped(const int* __restrict__ rp_p, const int* __restrict__ col_p,
                                 const int* __restrict__ mapv, const int* __restrict__ rp_c,
                                 int* __restrict__ col_c, int np){
  int d = blockIdx.x*blockDim.x + threadIdx.x;
  if (d >= np) return;
  int md = mapv[d];
  if (md < 0) return;
  int pos = rp_c[md], e = rp_p[d+1];
  for (int j = rp_p[d]; j < e; j++){
    int ms = mapv[col_p[j]];
    if (ms >= 0) col_c[pos++] = ms;
  }
}

// dinv[i] = rsqrt(indegree + fill)  (all edge weights are 1.0)
__global__ void k_dinv_rp(const int* __restrict__ rp, float* __restrict__ dinv,
                          float fill, int n){
  int i = blockIdx.x*blockDim.x + threadIdx.x;
  if (i < n) dinv[i] = 1.0f/sqrtf((float)(rp[i+1]-rp[i]) + fill);
}

// gather-based GCN aggregation: one wave per node, lane = feature
__global__ void k_gather_agg(const int* __restrict__ rp, const int* __restrict__ col,
                             const float* __restrict__ dinv, const float* __restrict__ h,
                             float* __restrict__ out, float fill, int n){
  int t = blockIdx.x*blockDim.x + threadIdx.x;
  int i = t >> 6, f = t & 63;
  if (i >= n) return;
  int beg = rp[i], end = rp[i+1];
  float di = dinv[i];
  float acc = 0.f;
  for (int j = beg; j < end; j++){
    int s = col[j];
    acc += dinv[s]*h[s*64+f];
  }
  out[i*64+f] = di*acc + fill*di*di*h[i*64+f];
}

// final conv (Fout=1, fill=1) fused with sigmoid; 1 thread per node
__global__ void k_gather_sig(const int* __restrict__ rp, const int* __restrict__ col,
                             const float* __restrict__ dinv, const float* __restrict__ h1,
                             float* __restrict__ out, int n){
  int i = blockIdx.x*blockDim.x + threadIdx.x;
  if (i >= n) return;
  int beg = rp[i], end = rp[i+1];
  float di = dinv[i];
  float acc = 0.f;
  for (int j = beg; j < end; j++){
    int s = col[j];
    acc += dinv[s]*h1[s];
  }
  float v = di*acc + di*di*h1[i];
  out[i] = 1.f/(1.f+expf(-v));
}

// per-channel sum & sumsq over rows -> stats[0:64]=sum, stats[64:128]=sumsq
__global__ void k_bnstats(const float* __restrict__ x, float* __restrict__ stats, int n) {
  __shared__ float ls[64], lq[64];
  int f = threadIdx.x & 63, rl = threadIdx.x >> 6;
  if (threadIdx.x < 64) { ls[threadIdx.x] = 0.f; lq[threadIdx.x] = 0.f; }
  __syncthreads();
  float s = 0.f, q = 0.f;
  for (int i = blockIdx.x*4 + rl; i < n; i += gridDim.x*4) {
    float v = x[i*64+f]; s += v; q += v*v;
  }
  atomicAdd(&ls[f], s); atomicAdd(&lq[f], q);
  __syncthreads();
  if (threadIdx.x < 64) {
    atomicAdd(&stats[threadIdx.x], ls[threadIdx.x]);
    atomicAdd(&stats[64+threadIdx.x], lq[threadIdx.x]);
  }
}

__global__ void k_bnrelu(float* __restrict__ x, const float* __restrict__ stats,
                         const float* __restrict__ gamma, const float* __restrict__ beta,
                         int n) {
  int t = blockIdx.x*blockDim.x + threadIdx.x;
  if (t >= n*64) return;
  int f = t & 63;
  float inv_n = 1.0f/(float)n;
  float mu = stats[f]*inv_n;
  float var = stats[64+f]*inv_n - mu*mu;
  float v = gamma[f]*(x[t]-mu)*(1.0f/sqrtf(var+1e-5f)) + beta[f];
  x[t] = fmaxf(v, 0.f);
}

__global__ void k_score(const float* __restrict__ x, const float* __restrict__ pw,
                        float* __restrict__ score, int n) {
  int i = blockIdx.x*blockDim.x + threadIdx.x;
  if (i >= n) return;
  float s = 0.f, q = 0.f;
  for (int k2 = 0; k2 < 64; k2++){ float w = pw[k2]; s += x[i*64+k2]*w; q += w*w; }
  score[i] = fmaxf(s/sqrtf(q), 0.f);
}

// ---- stable LSD radix sort (descending score, ties index-asc) ----
__global__ void k_radix_init(const float* __restrict__ score, unsigned* __restrict__ key,
                             int* __restrict__ idx, int n, int P){
  int g = blockIdx.x*blockDim.x + threadIdx.x;
  if (g >= P) return;
  if (g < n) { key[g] = ~__float_as_uint(score[g]); idx[g] = g; }
  else       { key[g] = 0xFFFFFFFFu; idx[g] = 0; }
}

__global__ void k_radix_hist(const unsigned* __restrict__ key, unsigned* __restrict__ hist,
                             int shift, int nblk){
  __shared__ unsigned lh[256];
  lh[threadIdx.x] = 0; __syncthreads();
  int g = blockIdx.x*256 + threadIdx.x;
  unsigned d = (key[g] >> shift) & 255u;
  atomicAdd(&lh[d], 1u);
  __syncthreads();
  hist[threadIdx.x*nblk + blockIdx.x] = lh[threadIdx.x];
}

__global__ void k_radix_scan(unsigned* __restrict__ hist, int nblk){
  __shared__ unsigned bs[256];
  int d = threadIdx.x;
  unsigned s = 0;
  for (int b = 0; b < nblk; b++) s += hist[d*nblk + b];
  bs[d] = s; __syncthreads();
  if (d == 0){ unsigned acc = 0; for (int i = 0; i < 256; i++){ unsigned t = bs[i]; bs[i] = acc; acc += t; } }
  __syncthreads();
  unsigned acc = bs[d];
  for (int b = 0; b < nblk; b++){ unsigned t = hist[d*nblk + b]; hist[d*nblk + b] = acc; acc += t; }
}

__global__ void k_radix_scatter(const unsigned* __restrict__ keyin, const int* __restrict__ idxin,
                                unsigned* __restrict__ keyout, int* __restrict__ idxout,
                                const unsigned* __restrict__ hist, int shift, int nblk){
  __shared__ unsigned ld[256];
  int g = blockIdx.x*256 + threadIdx.x;
  unsigned kk = keyin[g];
  int id = idxin[g];
  unsigned d = (kk >> shift) & 255u;
  ld[threadIdx.x] = d; __syncthreads();
  unsigned r = 0;
  for (int u = 0; u < threadIdx.x; u++) if (ld[u] == d) r++;
  unsigned pos = hist[d*nblk + blockIdx.x] + r;
  keyout[pos] = kk; idxout[pos] = id;
}

__global__ void k_select_sorted(const int* __restrict__ idxs, int* __restrict__ perm,
                                int* __restrict__ mapping, int n, int k){
  int r = blockIdx.x*blockDim.x + threadIdx.x;
  if (r >= n) return;
  int i = idxs[r];
  mapping[i] = (r < k) ? r : -1;
  if (r < k) perm[r] = i;
}

__global__ void k_gather_scale(const float* __restrict__ x, const float* __restrict__ score,
                               const int* __restrict__ perm, float* __restrict__ xk, int k) {
  int t = blockIdx.x*blockDim.x + threadIdx.x;
  if (t >= k*64) return;
  int r = t >> 6, f = t & 63;
  int i = perm[r];
  xk[t] = x[i*64+f]*score[i];
}

__global__ void k_scatter_add(const float* __restrict__ xup, const int* __restrict__ perm,
                              float* __restrict__ res, int k) {
  int t = blockIdx.x*blockDim.x + threadIdx.x;
  if (t >= k*64) return;
  int r = t >> 6, f = t & 63;
  res[perm[r]*64+f] += xup[t];
}

extern "C" void kernel_launch(void* const* d_in, const int* in_sizes, int n_in,
                              void* d_out, int out_size, void* d_ws, size_t ws_size,
                              hipStream_t stream) {
  const float* x_in = (const float*)d_in[0];
  const int* ei = (const int*)d_in[1];
  const int* src0 = ei;
  const int* dst0 = ei + NE;
  const float* W_d[4] = {(const float*)d_in[2],(const float*)d_in[5],(const float*)d_in[8],(const float*)d_in[11]};
  const float* g_d[4] = {(const float*)d_in[3],(const float*)d_in[6],(const float*)d_in[9],(const float*)d_in[12]};
  const float* b_d[4] = {(const float*)d_in[4],(const float*)d_in[7],(const float*)d_in[10],(const float*)d_in[13]};
  const float* pw[3]  = {(const float*)d_in[14],(const float*)d_in[15],(const float*)d_in[16]};
  const float* W_u[2] = {(const float*)d_in[17],(const float*)d_in[20]};
  const float* g_u[2] = {(const float*)d_in[18],(const float*)d_in[21]};
  const float* b_u[2] = {(const float*)d_in[19],(const float*)d_in[22]};
  const float* W_out  = (const float*)d_in[23];
  float* out = (float*)d_out;

  float* base = (float*)d_ws;
  size_t off = 0;
  auto alloc = [&](size_t nf){ float* p = base + off; off += nf; return p; };
  float* x0 = alloc(5120000);
  float* x1 = alloc(2560000);
  float* x2 = alloc(1280000);
  float* x3 = alloc(640000);
  float* A  = alloc(2560000);
  float* h  = alloc(5120000);
  int* col0 = (int*)alloc(NE);
  int* col1 = (int*)alloc(NE);
  int* col2 = (int*)alloc(NE);
  int* col3 = (int*)alloc(NE);
  int* rp0 = (int*)alloc(80001);
  int* rp1 = (int*)alloc(40001);
  int* rp2 = (int*)alloc(20001);
  int* rp3 = (int*)alloc(10001);
  int* indeg  = (int*)alloc(NN0);
  int* cursor = (int*)alloc(NN0);
  float* dinv  = alloc(NN0);
  float* score = alloc(NN0);
  int* mapv = (int*)alloc(NN0);
  int* p0 = (int*)alloc(40000);
  int* p1 = (int*)alloc(20000);
  int* p2 = (int*)alloc(10000);
  float* stats = alloc(128);
  unsigned* keyA = (unsigned*)alloc(80128);
  unsigned* keyB = (unsigned*)alloc(80128);
  int* idxA = (int*)alloc(80128);
  int* idxB = (int*)alloc(80128);
  unsigned* hist = (unsigned*)alloc(80128);
  (void)ws_size; (void)in_sizes; (void)n_in; (void)out_size;

  const int B = 256;

  auto conv = [&](const float* xin, const float* W, int Fin, int n, float fill,
                  const int* rp, const int* col, float* dstb){
    k_matmul    <<<cdiv(n*64,B), B, 0, stream>>>(xin, W, h, n, Fin, 64);
    k_dinv_rp   <<<cdiv(n,B),    B, 0, stream>>>(rp, dinv, fill, n);
    k_gather_agg<<<cdiv(n*64,B), B, 0, stream>>>(rp, col, dinv, h, dstb, fill, n);
  };

  auto bn_relu = [&](float* xb, const float* g, const float* bt, int n) {
    k_zero_f <<<1, 128, 0, stream>>>(stats, 128);
    k_bnstats<<<256, 256, 0, stream>>>(xb, stats, n);
    k_bnrelu <<<cdiv(n*64,B), B, 0, stream>>>(xb, stats, g, bt, n);
  };

  auto pool = [&](const float* xb, const float* w, int n, int k, int* pm, float* xk) {
    k_score<<<cdiv(n,B), B, 0, stream>>>(xb, w, score, n);
    int nblk = cdiv(n, 256), P = nblk*256;
    k_radix_init<<<cdiv(P,B), B, 0, stream>>>(score, keyA, idxA, n, P);
    unsigned* ka = keyA; int* ia = idxA; unsigned* kb = keyB; int* ib = idxB;
    for (int pass = 0; pass < 4; pass++) {
      k_radix_hist   <<<nblk, 256, 0, stream>>>(ka, hist, pass*8, nblk);
      k_radix_scan   <<<1,    256, 0, stream>>>(hist, nblk);
      k_radix_scatter<<<nblk, 256, 0, stream>>>(ka, ia, kb, ib, hist, pass*8, nblk);
      std::swap(ka, kb); std::swap(ia, ib);
    }
    k_select_sorted<<<cdiv(n,B), B, 0, stream>>>(ia, pm, mapv, n, k);
    k_gather_scale <<<cdiv(k*64,B), B, 0, stream>>>(xb, score, pm, xk, k);
  };

  auto csr_mapped = [&](const int* rp_p, const int* col_p, int np, int nc,
                        int* rp_c, int* col_c){
    k_hist_mapped   <<<cdiv(np,B), B, 0, stream>>>(rp_p, col_p, mapv, indeg, np);
    k_scan          <<<1, 256, 0, stream>>>(indeg, rp_c, cursor, nc);
    k_scatter_mapped<<<cdiv(np,B), B, 0, stream>>>(rp_p, col_p, mapv, rp_c, col_c, np);
  };

  // ---- CSR for level 0 ----
  k_zero_i      <<<cdiv(NN0,B), B, 0, stream>>>(indeg, NN0);
  k_hist_full   <<<cdiv(NE,B),  B, 0, stream>>>(dst0, indeg, NE);
  k_scan        <<<1, 256, 0, stream>>>(indeg, rp0, cursor, NN0);
  k_scatter_full<<<cdiv(NE,B),  B, 0, stream>>>(src0, dst0, cursor, col0, NE);

  // ---- down path ----
  conv(x_in, W_d[0], 3, NN0, 2.f, rp0, col0, x0);
  bn_relu(x0, g_d[0], b_d[0], NN0);

  pool(x0, pw[0], NN0, 40000, p0, A);
  csr_mapped(rp0, col0, NN0, 40000, rp1, col1);
  conv(A, W_d[1], 64, 40000, 2.f, rp1, col1, x1);
  bn_relu(x1, g_d[1], b_d[1], 40000);

  pool(x1, pw[1], 40000, 20000, p1, A);
  csr_mapped(rp1, col1, 40000, 20000, rp2, col2);
  conv(A, W_d[2], 64, 20000, 2.f, rp2, col2, x2);
  bn_relu(x2, g_d[2], b_d[2], 20000);

  pool(x2, pw[2], 20000, 10000, p2, A);
  csr_mapped(rp2, col2, 20000, 10000, rp3, col3);
  conv(A, W_d[3], 64, 10000, 2.f, rp3, col3, x3);
  bn_relu(x3, g_d[3], b_d[3], 10000);

  // ---- up path ----
  k_scatter_add<<<cdiv(10000*64,B), B, 0, stream>>>(x3, p2, x2, 10000);
  conv(x2, W_u[0], 64, 20000, 2.f, rp2, col2, A);
  bn_relu(A, g_u[0], b_u[0], 20000);

  k_scatter_add<<<cdiv(20000*64,B), B, 0, stream>>>(A, p1, x1, 20000);
  conv(x1, W_u[1], 64, 40000, 2.f, rp1, col1, A);
  bn_relu(A, g_u[1], b_u[1], 40000);

  k_scatter_add<<<cdiv(40000*64,B), B, 0, stream>>>(A, p0, x0, 40000);

  // ---- final conv (fill = 1.0) fused with sigmoid ----
  float* h1 = score;  // reuse
  k_matmul    <<<cdiv(NN0,B), B, 0, stream>>>(x0, W_out, h1, NN0, 64, 1);
  k_dinv_rp   <<<cdiv(NN0,B), B, 0, stream>>>(rp0, dinv, 1.f, NN0);
  k_gather_sig<<<cdiv(NN0,B), B, 0, stream>>>(rp0, col0, dinv, h1, out, NN0);
}

// Round 4
// 1222.510 us; speedup vs baseline: 4.6692x; 1.9473x over previous
//
#include <hip/hip_runtime.h>
#include <cstdint>
#include <utility>

#define NN0 80000
#define NE 1280000

static inline int cdiv(int a, int b){ return (a+b-1)/b; }

// h[n,Fout] = x[n,Fin] @ W[Fin,Fout]
__global__ void k_matmul(const float* __restrict__ x, const float* __restrict__ W,
                         float* __restrict__ h, int n, int Fin, int Fout) {
  int t = blockIdx.x*blockDim.x + threadIdx.x;
  if (t >= n*Fout) return;
  int i = t / Fout, f = t - i*Fout;
  float s = 0.f;
  for (int k2 = 0; k2 < Fin; k2++) s += x[i*Fin+k2]*W[k2*Fout+f];
  h[t] = s;
}

__global__ void k_zero_f(float* __restrict__ p, int n){
  int t = blockIdx.x*blockDim.x + threadIdx.x;
  if (t < n) p[t] = 0.f;
}
__global__ void k_zero_i(int* __restrict__ p, int n){
  int t = blockIdx.x*blockDim.x + threadIdx.x;
  if (t < n) p[t] = 0;
}

// ---- parallel exclusive scan (3 kernels, 1024 elems/block) ----
__global__ void k_scan_part(const int* __restrict__ in, int* __restrict__ bsum, int n){
  __shared__ int ws[256];
  int base = blockIdx.x*1024 + threadIdx.x*4;
  int s = 0;
  #pragma unroll
  for (int u = 0; u < 4; u++){ int i = base+u; if (i < n) s += in[i]; }
  ws[threadIdx.x] = s; __syncthreads();
  for (int st = 128; st > 0; st >>= 1){
    if (threadIdx.x < st) ws[threadIdx.x] += ws[threadIdx.x+st];
    __syncthreads();
  }
  if (threadIdx.x == 0) bsum[blockIdx.x] = ws[0];
}

// single block: exclusive scan of bsum[0..nb), nb <= 256
__global__ void k_scan_bsum(int* __restrict__ bsum, int nb){
  __shared__ int ws[256];
  int t = threadIdx.x;
  int v = (t < nb) ? bsum[t] : 0;
  ws[t] = v; __syncthreads();
  for (int st = 1; st < 256; st <<= 1){
    int a = (t >= st) ? ws[t-st] : 0; __syncthreads();
    ws[t] += a; __syncthreads();
  }
  if (t < nb) bsum[t] = ws[t] - v;
}

// final stage for CSR: writes rp[0..n], cursor[0..n)
__global__ void k_scan_rp(const int* __restrict__ in, const int* __restrict__ bsum,
                          int* __restrict__ rp, int* __restrict__ cursor, int n){
  __shared__ int ws[256];
  int t = threadIdx.x;
  int base = blockIdx.x*1024 + t*4;
  int v[4]; int s = 0;
  #pragma unroll
  for (int u = 0; u < 4; u++){ int i = base+u; v[u] = (i < n) ? in[i] : 0; s += v[u]; }
  ws[t] = s; __syncthreads();
  for (int st = 1; st < 256; st <<= 1){
    int a = (t >= st) ? ws[t-st] : 0; __syncthreads();
    ws[t] += a; __syncthreads();
  }
  int off = bsum[blockIdx.x] + ws[t] - s;
  #pragma unroll
  for (int u = 0; u < 4; u++){
    int i = base+u;
    if (i < n){
      rp[i] = off; cursor[i] = off; off += v[u];
      if (i == n-1) rp[n] = off;
    }
  }
}

// final stage, in-place flat scan (radix histogram)
__global__ void k_scan_inplace(int* __restrict__ data, const int* __restrict__ bsum, int n){
  __shared__ int ws[256];
  int t = threadIdx.x;
  int base = blockIdx.x*1024 + t*4;
  int v[4]; int s = 0;
  #pragma unroll
  for (int u = 0; u < 4; u++){ int i = base+u; v[u] = (i < n) ? data[i] : 0; s += v[u]; }
  ws[t] = s; __syncthreads();
  for (int st = 1; st < 256; st <<= 1){
    int a = (t >= st) ? ws[t-st] : 0; __syncthreads();
    ws[t] += a; __syncthreads();
  }
  int off = bsum[blockIdx.x] + ws[t] - s;
  #pragma unroll
  for (int u = 0; u < 4; u++){
    int i = base+u;
    if (i < n){ data[i] = off; off += v[u]; }
  }
}

// ---- CSR build, level 0 (full input edge list) ----
__global__ void k_hist_full(const int* __restrict__ dst, int* __restrict__ indeg, int ne){
  int e = blockIdx.x*blockDim.x + threadIdx.x;
  if (e < ne) atomicAdd(&indeg[dst[e]], 1);
}
__global__ void k_scatter_full(const int* __restrict__ src, const int* __restrict__ dst,
                               int* __restrict__ cursor, int* __restrict__ col, int ne){
  int e = blockIdx.x*blockDim.x + threadIdx.x;
  if (e >= ne) return;
  int pos = atomicAdd(&cursor[dst[e]], 1);
  col[pos] = src[e];
}

// ---- CSR build for pooled level from parent CSR + injective mapping ----
__global__ void k_hist_mapped(const int* __restrict__ rp_p, const int* __restrict__ col_p,
                              const int* __restrict__ mapv, int* __restrict__ indeg, int np){
  int d = blockIdx.x*blockDim.x + threadIdx.x;
  if (d >= np) return;
  int md = mapv[d];
  if (md < 0) return;
  int c = 0, e = rp_p[d+1];
  for (int j = rp_p[d]; j < e; j++) if (mapv[col_p[j]] >= 0) c++;
  indeg[md] = c;
}
__global__ void k_scatter_mapped(const int* __restrict__ rp_p, const int* __restrict__ col_p,
                                 const int* __restrict__ mapv, const int* __restrict__ rp_c,
                                 int* __restrict__ col_c, int np){
  int d = blockIdx.x*blockDim.x + threadIdx.x;
  if (d >= np) return;
  int md = mapv[d];
  if (md < 0) return;
  int pos = rp_c[md], e = rp_p[d+1];
  for (int j = rp_p[d]; j < e; j++){
    int ms = mapv[col_p[j]];
    if (ms >= 0) col_c[pos++] = ms;
  }
}

// dinv[i] = rsqrt(indegree + fill)  (all edge weights are 1.0)
__global__ void k_dinv_rp(const int* __restrict__ rp, float* __restrict__ dinv,
                          float fill, int n){
  int i = blockIdx.x*blockDim.x + threadIdx.x;
  if (i < n) dinv[i] = 1.0f/sqrtf((float)(rp[i+1]-rp[i]) + fill);
}

// gather-based GCN aggregation: one wave per node, lane = feature
__global__ void k_gather_agg(const int* __restrict__ rp, const int* __restrict__ col,
                             const float* __restrict__ dinv, const float* __restrict__ h,
                             float* __restrict__ out, float fill, int n){
  int t = blockIdx.x*blockDim.x + threadIdx.x;
  int i = t >> 6, f = t & 63;
  if (i >= n) return;
  int beg = rp[i], end = rp[i+1];
  float di = dinv[i];
  float acc = 0.f;
  for (int j = beg; j < end; j++){
    int s = col[j];
    acc += dinv[s]*h[s*64+f];
  }
  out[i*64+f] = di*acc + fill*di*di*h[i*64+f];
}

// final conv (Fout=1, fill=1) fused with sigmoid; 1 thread per node
__global__ void k_gather_sig(const int* __restrict__ rp, const int* __restrict__ col,
                             const float* __restrict__ dinv, const float* __restrict__ h1,
                             float* __restrict__ out, int n){
  int i = blockIdx.x*blockDim.x + threadIdx.x;
  if (i >= n) return;
  int beg = rp[i], end = rp[i+1];
  float di = dinv[i];
  float acc = 0.f;
  for (int j = beg; j < end; j++){
    int s = col[j];
    acc += dinv[s]*h1[s];
  }
  float v = di*acc + di*di*h1[i];
  out[i] = 1.f/(1.f+expf(-v));
}

// per-channel sum & sumsq over rows -> stats[0:64]=sum, stats[64:128]=sumsq
__global__ void k_bnstats(const float* __restrict__ x, float* __restrict__ stats, int n) {
  __shared__ float ls[64], lq[64];
  int f = threadIdx.x & 63, rl = threadIdx.x >> 6;
  if (threadIdx.x < 64) { ls[threadIdx.x] = 0.f; lq[threadIdx.x] = 0.f; }
  __syncthreads();
  float s = 0.f, q = 0.f;
  for (int i = blockIdx.x*4 + rl; i < n; i += gridDim.x*4) {
    float v = x[i*64+f]; s += v; q += v*v;
  }
  atomicAdd(&ls[f], s); atomicAdd(&lq[f], q);
  __syncthreads();
  if (threadIdx.x < 64) {
    atomicAdd(&stats[threadIdx.x], ls[threadIdx.x]);
    atomicAdd(&stats[64+threadIdx.x], lq[threadIdx.x]);
  }
}

__global__ void k_bnrelu(float* __restrict__ x, const float* __restrict__ stats,
                         const float* __restrict__ gamma, const float* __restrict__ beta,
                         int n) {
  int t = blockIdx.x*blockDim.x + threadIdx.x;
  if (t >= n*64) return;
  int f = t & 63;
  float inv_n = 1.0f/(float)n;
  float mu = stats[f]*inv_n;
  float var = stats[64+f]*inv_n - mu*mu;
  float v = gamma[f]*(x[t]-mu)*(1.0f/sqrtf(var+1e-5f)) + beta[f];
  x[t] = fmaxf(v, 0.f);
}

__global__ void k_score(const float* __restrict__ x, const float* __restrict__ pw,
                        float* __restrict__ score, int n) {
  int i = blockIdx.x*blockDim.x + threadIdx.x;
  if (i >= n) return;
  float s = 0.f, q = 0.f;
  for (int k2 = 0; k2 < 64; k2++){ float w = pw[k2]; s += x[i*64+k2]*w; q += w*w; }
  score[i] = fmaxf(s/sqrtf(q), 0.f);
}

// ---- stable LSD radix sort (descending score, ties index-asc) ----
__global__ void k_radix_init(const float* __restrict__ score, unsigned* __restrict__ key,
                             int* __restrict__ idx, int n, int P){
  int g = blockIdx.x*blockDim.x + threadIdx.x;
  if (g >= P) return;
  if (g < n) { key[g] = ~__float_as_uint(score[g]); idx[g] = g; }
  else       { key[g] = 0xFFFFFFFFu; idx[g] = 0; }
}

__global__ void k_radix_hist(const unsigned* __restrict__ key, int* __restrict__ hist,
                             int shift, int nblk){
  __shared__ int lh[256];
  lh[threadIdx.x] = 0; __syncthreads();
  int g = blockIdx.x*256 + threadIdx.x;
  unsigned d = (key[g] >> shift) & 255u;
  atomicAdd(&lh[d], 1);
  __syncthreads();
  hist[threadIdx.x*nblk + blockIdx.x] = lh[threadIdx.x];
}

__global__ void k_radix_scatter(const unsigned* __restrict__ keyin, const int* __restrict__ idxin,
                                unsigned* __restrict__ keyout, int* __restrict__ idxout,
                                const int* __restrict__ hist, int shift, int nblk){
  __shared__ unsigned ld[256];
  int g = blockIdx.x*256 + threadIdx.x;
  unsigned kk = keyin[g];
  int id = idxin[g];
  unsigned d = (kk >> shift) & 255u;
  ld[threadIdx.x] = d; __syncthreads();
  unsigned r = 0;
  for (int u = 0; u < threadIdx.x; u++) if (ld[u] == d) r++;
  unsigned pos = hist[d*nblk + blockIdx.x] + r;
  keyout[pos] = kk; idxout[pos] = id;
}

__global__ void k_select_sorted(const int* __restrict__ idxs, int* __restrict__ perm,
                                int* __restrict__ mapping, int n, int k){
  int r = blockIdx.x*blockDim.x + threadIdx.x;
  if (r >= n) return;
  int i = idxs[r];
  mapping[i] = (r < k) ? r : -1;
  if (r < k) perm[r] = i;
}

__global__ void k_gather_scale(const float* __restrict__ x, const float* __restrict__ score,
                               const int* __restrict__ perm, float* __restrict__ xk, int k) {
  int t = blockIdx.x*blockDim.x + threadIdx.x;
  if (t >= k*64) return;
  int r = t >> 6, f = t & 63;
  int i = perm[r];
  xk[t] = x[i*64+f]*score[i];
}

__global__ void k_scatter_add(const float* __restrict__ xup, const int* __restrict__ perm,
                              float* __restrict__ res, int k) {
  int t = blockIdx.x*blockDim.x + threadIdx.x;
  if (t >= k*64) return;
  int r = t >> 6, f = t & 63;
  res[perm[r]*64+f] += xup[t];
}

extern "C" void kernel_launch(void* const* d_in, const int* in_sizes, int n_in,
                              void* d_out, int out_size, void* d_ws, size_t ws_size,
                              hipStream_t stream) {
  const float* x_in = (const float*)d_in[0];
  const int* ei = (const int*)d_in[1];
  const int* src0 = ei;
  const int* dst0 = ei + NE;
  const float* W_d[4] = {(const float*)d_in[2],(const float*)d_in[5],(const float*)d_in[8],(const float*)d_in[11]};
  const float* g_d[4] = {(const float*)d_in[3],(const float*)d_in[6],(const float*)d_in[9],(const float*)d_in[12]};
  const float* b_d[4] = {(const float*)d_in[4],(const float*)d_in[7],(const float*)d_in[10],(const float*)d_in[13]};
  const float* pw[3]  = {(const float*)d_in[14],(const float*)d_in[15],(const float*)d_in[16]};
  const float* W_u[2] = {(const float*)d_in[17],(const float*)d_in[20]};
  const float* g_u[2] = {(const float*)d_in[18],(const float*)d_in[21]};
  const float* b_u[2] = {(const float*)d_in[19],(const float*)d_in[22]};
  const float* W_out  = (const float*)d_in[23];
  float* out = (float*)d_out;

  float* base = (float*)d_ws;
  size_t off = 0;
  auto alloc = [&](size_t nf){ float* p = base + off; off += nf; return p; };
  float* x0 = alloc(5120000);
  float* x1 = alloc(2560000);
  float* x2 = alloc(1280000);
  float* x3 = alloc(640000);
  float* A  = alloc(2560000);
  float* h  = alloc(5120000);
  int* col0 = (int*)alloc(NE);
  int* col1 = (int*)alloc(NE);
  int* col2 = (int*)alloc(NE);
  int* col3 = (int*)alloc(NE);
  int* rp0 = (int*)alloc(80001);
  int* rp1 = (int*)alloc(40001);
  int* rp2 = (int*)alloc(20001);
  int* rp3 = (int*)alloc(10001);
  int* indeg  = (int*)alloc(NN0);
  int* cursor = (int*)alloc(NN0);
  float* dinv  = alloc(NN0);
  float* score = alloc(NN0);
  int* mapv = (int*)alloc(NN0);
  int* p0 = (int*)alloc(40000);
  int* p1 = (int*)alloc(20000);
  int* p2 = (int*)alloc(10000);
  float* stats = alloc(128);
  unsigned* keyA = (unsigned*)alloc(80128);
  unsigned* keyB = (unsigned*)alloc(80128);
  int* idxA = (int*)alloc(80128);
  int* idxB = (int*)alloc(80128);
  int* hist = (int*)alloc(80128);
  int* bsum = (int*)alloc(256);
  (void)ws_size; (void)in_sizes; (void)n_in; (void)out_size;

  const int B = 256;

  // parallel exclusive scan helpers
  auto scan_csr = [&](const int* indeg_, int* rp, int* cur, int n2){
    int nb = cdiv(n2, 1024);
    k_scan_part<<<nb, 256, 0, stream>>>(indeg_, bsum, n2);
    k_scan_bsum<<<1,  256, 0, stream>>>(bsum, nb);
    k_scan_rp  <<<nb, 256, 0, stream>>>(indeg_, bsum, rp, cur, n2);
  };
  auto scan_flat = [&](int* data, int n2){
    int nb = cdiv(n2, 1024);
    k_scan_part   <<<nb, 256, 0, stream>>>(data, bsum, n2);
    k_scan_bsum   <<<1,  256, 0, stream>>>(bsum, nb);
    k_scan_inplace<<<nb, 256, 0, stream>>>(data, bsum, n2);
  };

  auto conv = [&](const float* xin, const float* W, int Fin, int n, float fill,
                  const int* rp, const int* col, float* dstb){
    k_matmul    <<<cdiv(n*64,B), B, 0, stream>>>(xin, W, h, n, Fin, 64);
    k_dinv_rp   <<<cdiv(n,B),    B, 0, stream>>>(rp, dinv, fill, n);
    k_gather_agg<<<cdiv(n*64,B), B, 0, stream>>>(rp, col, dinv, h, dstb, fill, n);
  };

  auto bn_relu = [&](float* xb, const float* g, const float* bt, int n) {
    k_zero_f <<<1, 128, 0, stream>>>(stats, 128);
    k_bnstats<<<256, 256, 0, stream>>>(xb, stats, n);
    k_bnrelu <<<cdiv(n*64,B), B, 0, stream>>>(xb, stats, g, bt, n);
  };

  auto pool = [&](const float* xb, const float* w, int n, int k, int* pm, float* xk) {
    k_score<<<cdiv(n,B), B, 0, stream>>>(xb, w, score, n);
    int nblk = cdiv(n, 256), P = nblk*256;
    k_radix_init<<<cdiv(P,B), B, 0, stream>>>(score, keyA, idxA, n, P);
    unsigned* ka = keyA; int* ia = idxA; unsigned* kb = keyB; int* ib = idxB;
    for (int pass = 0; pass < 4; pass++) {
      k_radix_hist<<<nblk, 256, 0, stream>>>(ka, hist, pass*8, nblk);
      scan_flat(hist, nblk*256);
      k_radix_scatter<<<nblk, 256, 0, stream>>>(ka, ia, kb, ib, hist, pass*8, nblk);
      std::swap(ka, kb); std::swap(ia, ib);
    }
    k_select_sorted<<<cdiv(n,B), B, 0, stream>>>(ia, pm, mapv, n, k);
    k_gather_scale <<<cdiv(k*64,B), B, 0, stream>>>(xb, score, pm, xk, k);
  };

  auto csr_mapped = [&](const int* rp_p, const int* col_p, int np, int nc,
                        int* rp_c, int* col_c){
    k_hist_mapped<<<cdiv(np,B), B, 0, stream>>>(rp_p, col_p, mapv, indeg, np);
    scan_csr(indeg, rp_c, cursor, nc);
    k_scatter_mapped<<<cdiv(np,B), B, 0, stream>>>(rp_p, col_p, mapv, rp_c, col_c, np);
  };

  // ---- CSR for level 0 ----
  k_zero_i   <<<cdiv(NN0,B), B, 0, stream>>>(indeg, NN0);
  k_hist_full<<<cdiv(NE,B),  B, 0, stream>>>(dst0, indeg, NE);
  scan_csr(indeg, rp0, cursor, NN0);
  k_scatter_full<<<cdiv(NE,B), B, 0, stream>>>(src0, dst0, cursor, col0, NE);

  // ---- down path ----
  conv(x_in, W_d[0], 3, NN0, 2.f, rp0, col0, x0);
  bn_relu(x0, g_d[0], b_d[0], NN0);

  pool(x0, pw[0], NN0, 40000, p0, A);
  csr_mapped(rp0, col0, NN0, 40000, rp1, col1);
  conv(A, W_d[1], 64, 40000, 2.f, rp1, col1, x1);
  bn_relu(x1, g_d[1], b_d[1], 40000);

  pool(x1, pw[1], 40000, 20000, p1, A);
  csr_mapped(rp1, col1, 40000, 20000, rp2, col2);
  conv(A, W_d[2], 64, 20000, 2.f, rp2, col2, x2);
  bn_relu(x2, g_d[2], b_d[2], 20000);

  pool(x2, pw[2], 20000, 10000, p2, A);
  csr_mapped(rp2, col2, 20000, 10000, rp3, col3);
  conv(A, W_d[3], 64, 10000, 2.f, rp3, col3, x3);
  bn_relu(x3, g_d[3], b_d[3], 10000);

  // ---- up path ----
  k_scatter_add<<<cdiv(10000*64,B), B, 0, stream>>>(x3, p2, x2, 10000);
  conv(x2, W_u[0], 64, 20000, 2.f, rp2, col2, A);
  bn_relu(A, g_u[0], b_u[0], 20000);

  k_scatter_add<<<cdiv(20000*64,B), B, 0, stream>>>(A, p1, x1, 20000);
  conv(x1, W_u[1], 64, 40000, 2.f, rp1, col1, A);
  bn_relu(A, g_u[1], b_u[1], 40000);

  k_scatter_add<<<cdiv(40000*64,B), B, 0, stream>>>(A, p0, x0, 40000);

  // ---- final conv (fill = 1.0) fused with sigmoid ----
  float* h1 = score;  // reuse
  k_matmul    <<<cdiv(NN0,B), B, 0, stream>>>(x0, W_out, h1, NN0, 64, 1);
  k_dinv_rp   <<<cdiv(NN0,B), B, 0, stream>>>(rp0, dinv, 1.f, NN0);
  k_gather_sig<<<cdiv(NN0,B), B, 0, stream>>>(rp0, col0, dinv, h1, out, NN0);
}